// Round 8
// baseline (305.180 us; speedup 1.0000x reference)
//
#include <hip/hip_runtime.h>
#include <cstddef>
#include <cstdint>

#define NUSERS 50000
#define NITEMS 50000
#define NNODES 100000
#define DIM    128
#define NLAYERS 3
#define NEDGES 600000
#define NPAD 100096           // 391*256  (>=96 rows of slack past NNODES)

#define EBLK  8192            // edges per binning block
#define NBLK  74              // ceil(600000/8192)
#define NBUCK 782             // ceil(100000/128), bucket = dst>>7

typedef __attribute__((ext_vector_type(8))) short short8;
typedef __attribute__((ext_vector_type(4))) float f32x4;

__device__ __forceinline__ float bf_lo(unsigned u) { return __uint_as_float(u << 16); }
__device__ __forceinline__ float bf_hi(unsigned u) { return __uint_as_float(u & 0xffff0000u); }
__device__ __forceinline__ unsigned short f2bf(float f) {      // round-nearest-even
    unsigned b = __float_as_uint(f);
    return (unsigned short)((b + 0x7fffu + ((b >> 16) & 1u)) >> 16);
}

// async global->LDS 16B per lane; dst must be wave-uniform base (HW adds lane*16)
__device__ __forceinline__ void async16(const void* g, void* l) {
    __builtin_amdgcn_global_load_lds(
        (const __attribute__((address_space(1))) unsigned int*)(uintptr_t)g,
        (__attribute__((address_space(3))) unsigned int*)(unsigned int)(uintptr_t)l,
        16, 0, 0);
}

// ---------------------------------------------------------------------------
// concat user/item embeddings into bf16 shadow xb [N,128]
// ---------------------------------------------------------------------------
__global__ void concat_kernel(const float* __restrict__ ue,
                              const float* __restrict__ ie,
                              unsigned short* __restrict__ xb) {
    int i = blockIdx.x * blockDim.x + threadIdx.x;      // group of 4 elements
    const int uq = NUSERS * DIM / 4;
    const int tq = NNODES * DIM / 4;
    if (i < tq) {
        float4 v = (i < uq) ? ((const float4*)ue)[i]
                            : ((const float4*)ie)[i - uq];
        ushort4 o = make_ushort4(f2bf(v.x), f2bf(v.y), f2bf(v.z), f2bf(v.w));
        *(ushort4*)(xb + (size_t)i * 4) = o;
    }
}

// ---------------------------------------------------------------------------
// Bf[l][nb][ks][nf][lane][8] = Wg[l][k][col] in MFMA B-fragment order
// ---------------------------------------------------------------------------
__global__ void wg_conv_kernel(const float* __restrict__ Wg,
                               unsigned short* __restrict__ Bf) {
    const int tid = blockIdx.x * blockDim.x + threadIdx.x;   // one per 8 elems
    if (tid >= NLAYERS * 4096) return;
    const int l    = tid >> 12;
    const int slot = tid & 4095;
    const int lane = slot & 63;
    const int t2   = slot >> 6;
    const int nf   = t2 & 3;
    const int t3   = t2 >> 2;
    const int ks   = t3 & 7;
    const int nb   = t3 >> 3;
    const int col  = nb * 64 + nf * 16 + (lane & 15);
    const int k0   = ks * 32 + (lane >> 4) * 8;
    const float* wsrc = Wg + (size_t)l * 256 * DIM;
    unsigned short o[8];
    #pragma unroll
    for (int j = 0; j < 8; ++j) o[j] = f2bf(wsrc[(size_t)(k0 + j) * DIM + col]);
    *(short8*)(Bf + (size_t)tid * 8) = *(short8*)o;
}

// ---------------------------------------------------------------------------
// binned CSR build
// ---------------------------------------------------------------------------
__global__ __launch_bounds__(256) void bin_count_kernel(
        const int* __restrict__ dst, unsigned* __restrict__ counts) {
    __shared__ unsigned hist[NBUCK];
    for (int i = threadIdx.x; i < NBUCK; i += 256) hist[i] = 0;
    __syncthreads();
    const int base = blockIdx.x * EBLK;
    const int end  = (base + EBLK < NEDGES) ? base + EBLK : NEDGES;
    for (int e = base + threadIdx.x; e < end; e += 256)
        atomicAdd(&hist[dst[e] >> 7], 1u);
    __syncthreads();
    for (int i = threadIdx.x; i < NBUCK; i += 256)
        counts[(size_t)blockIdx.x * NBUCK + i] = hist[i];
}

// merged: per-bucket column prefix over blocks + exclusive scan of totals
__global__ __launch_bounds__(1024) void prefix_kernel(
        unsigned* __restrict__ counts, unsigned* __restrict__ bucketbase) {
    const int b = threadIdx.x;
    unsigned tot = 0;
    if (b < NBUCK) {
        for (int i = 0; i < NBLK; ++i) {
            const unsigned c = counts[(size_t)i * NBUCK + b];
            counts[(size_t)i * NBUCK + b] = tot;
            tot += c;
        }
    }
    const int lane = b & 63, w = b >> 6;
    unsigned s = tot;
    #pragma unroll
    for (int o = 1; o < 64; o <<= 1) {
        unsigned t = (unsigned)__shfl_up((int)s, o);
        if (lane >= o) s += t;
    }
    __shared__ unsigned wsum[16];
    if (lane == 63) wsum[w] = s;
    __syncthreads();
    unsigned add = 0;
    #pragma unroll
    for (int j = 0; j < 15; ++j) if (w > j) add += wsum[j];
    if (b < NBUCK) bucketbase[b] = s + add - tot;
    if (b == NBUCK - 1) bucketbase[NBUCK] = s + add;   // == NEDGES
}

__global__ __launch_bounds__(256) void bin_scatter_kernel(
        const int* __restrict__ src, const int* __restrict__ dst,
        const unsigned* __restrict__ counts, const unsigned* __restrict__ bucketbase,
        unsigned* __restrict__ pairs) {
    __shared__ unsigned off[NBUCK];
    for (int i = threadIdx.x; i < NBUCK; i += 256)
        off[i] = bucketbase[i] + counts[(size_t)blockIdx.x * NBUCK + i];
    __syncthreads();
    const int base = blockIdx.x * EBLK;
    const int end  = (base + EBLK < NEDGES) ? base + EBLK : NEDGES;
    for (int e = base + threadIdx.x; e < end; e += 256) {
        const int d = dst[e];
        const unsigned pos = atomicAdd(&off[d >> 7], 1u);
        pairs[pos] = ((unsigned)(d & 127) << 17) | (unsigned)src[e];
    }
}

__global__ __launch_bounds__(256) void bucket_csr_kernel(
        const unsigned* __restrict__ pairs, const unsigned* __restrict__ bucketbase,
        int* __restrict__ row_start, int* __restrict__ csr_src) {
    __shared__ unsigned deg[128], rs[128], fill[128];
    const int b = blockIdx.x;
    const unsigned seg0 = bucketbase[b], seg1 = bucketbase[b + 1];
    const int t = threadIdx.x;
    if (t < 128) deg[t] = 0;
    __syncthreads();
    for (unsigned i = seg0 + t; i < seg1; i += 256)
        atomicAdd(&deg[pairs[i] >> 17], 1u);
    __syncthreads();
    if (t < 128) rs[t] = deg[t];
    __syncthreads();
    #pragma unroll
    for (int o = 1; o < 128; o <<= 1) {           // Hillis-Steele inclusive
        unsigned tmp = 0;
        if (t < 128 && t >= o) tmp = rs[t - o];
        __syncthreads();
        if (t < 128) rs[t] += tmp;
        __syncthreads();
    }
    if (t < 128) {
        const unsigned excl = rs[t] - deg[t];
        fill[t] = excl;
        const int node = b * 128 + t;
        if (node < NNODES) row_start[node] = (int)(seg0 + excl);
    }
    __syncthreads();
    for (unsigned i = seg0 + t; i < seg1; i += 256) {
        const unsigned p = pairs[i];
        const unsigned r = atomicAdd(&fill[p >> 17], 1u);
        csr_src[seg0 + r] = (int)(p & 0x1ffffu);
    }
    if (b == 0 && t == 0) row_start[NNODES] = NEDGES;
}

// ---------------------------------------------------------------------------
// layer-0 attention halves (subsequent layers fused into layer_kernel epilogue)
// ---------------------------------------------------------------------------
__global__ __launch_bounds__(256) void node_dots_kernel(
        const unsigned short* __restrict__ xb, const float* __restrict__ Wa,
        const float* __restrict__ ba,
        float* __restrict__ a_src, float* __restrict__ a_dst) {
    const int n = (blockIdx.x * blockDim.x + threadIdx.x) >> 6;
    if (n >= NNODES) return;
    const int lane = threadIdx.x & 63;
    const unsigned u = *(const unsigned*)(xb + (size_t)n * DIM + lane * 2);
    const float x0 = bf_lo(u), x1 = bf_hi(u);
    const float2 wlo = *(const float2*)(Wa + lane * 2);
    const float2 whi = *(const float2*)(Wa + DIM + lane * 2);
    float ps = x0 * wlo.x + x1 * wlo.y;
    float pd = x0 * whi.x + x1 * whi.y;
    #pragma unroll
    for (int o = 32; o; o >>= 1) { ps += __shfl_xor(ps, o); pd += __shfl_xor(pd, o); }
    if (lane == 0) { a_src[n] = ps; a_dst[n] = pd + ba[0]; }
}

// ---------------------------------------------------------------------------
// FUSED layer: pull-aggregate (into LDS) + MFMA GEMM + ReLU + next-layer dots
//   block = 128 rows, 256 thr (4 waves 2x2).
//   phase 1: async-DMA xin rows -> At[0] (XOR-swizzled via source address)
//   phase 2: quarter-wave gather computes agg rows -> ds_write (same swizzle)
//   phase 3: 8 MFMA K-steps from LDS (B frags reg-double-buffered from global)
//   phase 4: bias+relu store + fused a_src/a_dst for next layer
// ---------------------------------------------------------------------------
__global__ __launch_bounds__(256) void layer_kernel(
        const unsigned short* __restrict__ xin,
        const int* __restrict__ row_start, const int* __restrict__ csr_src,
        const float* __restrict__ a_src, const float* __restrict__ a_dst,
        const unsigned short* __restrict__ bfr, const float* __restrict__ bg,
        const float* __restrict__ wa_next, const float* __restrict__ ba_next,
        float* __restrict__ a_src_next, float* __restrict__ a_dst_next,
        float* __restrict__ xout_f32, unsigned short* __restrict__ xout_bf,
        int write_f32, int do_dots) {
    __shared__ unsigned short At[2][128 * 128];     // 64 KB
    __shared__ float psS[2][128], psD[2][128];      // 2 KB

    const int tid  = threadIdx.x;
    const int lane = tid & 63;
    const int wid  = tid >> 6;
    const int mbase = blockIdx.x * 128;

    // ---- phase 1: async-stage xin (K 0..127) ----
    #pragma unroll
    for (int i = 0; i < 8; ++i) {
        const int lrow = i * 16 + wid * 4 + (lane >> 4);
        const int c    = (lane & 15) ^ (lrow & 7);
        async16(xin + (size_t)(mbase + lrow) * DIM + c * 8,
                &At[0][(i * 16 + wid * 4) * 128]);
    }

    // ---- phase 2: gather agg for this block's rows, straight into At[1] ----
    {
        const int q   = tid >> 4;          // quarter 0..15
        const int sub = lane & 15;
        const int qb  = lane & 48;
        for (int it = 0; it < 8; ++it) {
            const int n = mbase + it * 16 + q;
            float a0 = 0, a1 = 0, a2 = 0, a3 = 0, a4 = 0, a5 = 0, a6 = 0, a7 = 0;
            if (n < NNODES) {
                const int beg = row_start[n], end = row_start[n + 1];
                const float adst = a_dst[n];
                for (int base = beg; base < end; base += 16) {
                    const int rem = end - base;
                    const int cnt = rem < 16 ? rem : 16;
                    int   idx_l = 0;
                    float att_l = 0.0f;
                    if (sub < cnt) {
                        idx_l = csr_src[base + sub];
                        att_l = 1.0f / (1.0f + __expf(-(a_src[idx_l] + adst)));
                    }
                    int i = 0;
                    for (; i + 3 < cnt; i += 4) {
                        const int   s0 = __shfl(idx_l, qb + i);
                        const int   s1 = __shfl(idx_l, qb + i + 1);
                        const int   s2 = __shfl(idx_l, qb + i + 2);
                        const int   s3 = __shfl(idx_l, qb + i + 3);
                        const float w0 = __shfl(att_l, qb + i);
                        const float w1 = __shfl(att_l, qb + i + 1);
                        const float w2 = __shfl(att_l, qb + i + 2);
                        const float w3 = __shfl(att_l, qb + i + 3);
                        const uint4 u0 = *(const uint4*)(xin + (size_t)s0 * DIM + sub * 8);
                        const uint4 u1 = *(const uint4*)(xin + (size_t)s1 * DIM + sub * 8);
                        const uint4 u2 = *(const uint4*)(xin + (size_t)s2 * DIM + sub * 8);
                        const uint4 u3 = *(const uint4*)(xin + (size_t)s3 * DIM + sub * 8);
                        a0 += bf_lo(u0.x) * w0 + bf_lo(u1.x) * w1 + bf_lo(u2.x) * w2 + bf_lo(u3.x) * w3;
                        a1 += bf_hi(u0.x) * w0 + bf_hi(u1.x) * w1 + bf_hi(u2.x) * w2 + bf_hi(u3.x) * w3;
                        a2 += bf_lo(u0.y) * w0 + bf_lo(u1.y) * w1 + bf_lo(u2.y) * w2 + bf_lo(u3.y) * w3;
                        a3 += bf_hi(u0.y) * w0 + bf_hi(u1.y) * w1 + bf_hi(u2.y) * w2 + bf_hi(u3.y) * w3;
                        a4 += bf_lo(u0.z) * w0 + bf_lo(u1.z) * w1 + bf_lo(u2.z) * w2 + bf_lo(u3.z) * w3;
                        a5 += bf_hi(u0.z) * w0 + bf_hi(u1.z) * w1 + bf_hi(u2.z) * w2 + bf_hi(u3.z) * w3;
                        a6 += bf_lo(u0.w) * w0 + bf_lo(u1.w) * w1 + bf_lo(u2.w) * w2 + bf_lo(u3.w) * w3;
                        a7 += bf_hi(u0.w) * w0 + bf_hi(u1.w) * w1 + bf_hi(u2.w) * w2 + bf_hi(u3.w) * w3;
                    }
                    for (; i < cnt; ++i) {
                        const int   s = __shfl(idx_l, qb + i);
                        const float w = __shfl(att_l, qb + i);
                        const uint4 u = *(const uint4*)(xin + (size_t)s * DIM + sub * 8);
                        a0 += bf_lo(u.x) * w;  a1 += bf_hi(u.x) * w;
                        a2 += bf_lo(u.y) * w;  a3 += bf_hi(u.y) * w;
                        a4 += bf_lo(u.z) * w;  a5 += bf_hi(u.z) * w;
                        a6 += bf_lo(u.w) * w;  a7 += bf_hi(u.w) * w;
                    }
                }
            }
            uint4 o;
            o.x = ((unsigned)f2bf(a1) << 16) | (unsigned)f2bf(a0);
            o.y = ((unsigned)f2bf(a3) << 16) | (unsigned)f2bf(a2);
            o.z = ((unsigned)f2bf(a5) << 16) | (unsigned)f2bf(a4);
            o.w = ((unsigned)f2bf(a7) << 16) | (unsigned)f2bf(a6);
            const int rl = it * 16 + q;
            *(uint4*)&At[1][rl * 128 + ((sub ^ (rl & 7)) << 3)] = o;
        }
    }

    asm volatile("s_waitcnt vmcnt(0) lgkmcnt(0)" ::: "memory");
    __builtin_amdgcn_s_barrier();

    // ---- phase 3: MFMA ----
    const int waveM = wid >> 1, waveN = wid & 1;
    const int l16 = lane & 15, kq = lane >> 4;
    const unsigned short* bfw = bfr + (size_t)(waveN * 8) * 4 * 64 * 8;

    f32x4 acc[4][4] = {};
    short8 bcur[4], bnxt[4];
    #pragma unroll
    for (int nf = 0; nf < 4; ++nf)
        bcur[nf] = *(const short8*)(bfw + ((size_t)(0 * 4 + nf) * 64 + lane) * 8);

    #pragma unroll
    for (int ks = 0; ks < 8; ++ks) {
        if (ks < 7) {
            #pragma unroll
            for (int nf = 0; nf < 4; ++nf)
                bnxt[nf] = *(const short8*)(bfw + ((size_t)((ks + 1) * 4 + nf) * 64 + lane) * 8);
        }
        const int h = ks >> 2, ksl = ks & 3;
        short8 a[4];
        #pragma unroll
        for (int mf = 0; mf < 4; ++mf) {
            const int row   = waveM * 64 + mf * 16 + l16;
            const int chunk = (ksl * 4 + kq) ^ (row & 7);
            a[mf] = *(const short8*)&At[h][row * 128 + chunk * 8];
        }
        #pragma unroll
        for (int mf = 0; mf < 4; ++mf)
            #pragma unroll
            for (int nf = 0; nf < 4; ++nf)
                acc[mf][nf] = __builtin_amdgcn_mfma_f32_16x16x32_bf16(
                    a[mf], bcur[nf], acc[mf][nf], 0, 0, 0);
        if (ks < 7) {
            #pragma unroll
            for (int nf = 0; nf < 4; ++nf) bcur[nf] = bnxt[nf];
        }
    }

    // ---- phase 4: epilogue (bias+relu store, fused next-layer dots) ----
    const int rsub = kq * 4;
    float waS[4] = {0, 0, 0, 0}, waD[4] = {0, 0, 0, 0}, bias[4];
    #pragma unroll
    for (int nf = 0; nf < 4; ++nf) {
        const int col = waveN * 64 + nf * 16 + l16;
        bias[nf] = bg[col];
        if (do_dots) { waS[nf] = wa_next[col]; waD[nf] = wa_next[DIM + col]; }
    }
    #pragma unroll
    for (int mf = 0; mf < 4; ++mf) {
        #pragma unroll
        for (int j = 0; j < 4; ++j) {
            const int row = mbase + waveM * 64 + mf * 16 + rsub + j;
            float s = 0.0f, d = 0.0f;
            #pragma unroll
            for (int nf = 0; nf < 4; ++nf) {
                const int col = waveN * 64 + nf * 16 + l16;
                const float v = fmaxf(acc[mf][nf][j] + bias[nf], 0.0f);
                if (write_f32) {
                    if (row < NNODES) xout_f32[(size_t)row * DIM + col] = v;
                } else {
                    const unsigned short bv = f2bf(v);
                    const unsigned pb = (unsigned)(unsigned short)__shfl_xor((int)bv, 1);
                    if (!(l16 & 1) && row < NNODES)
                        *(unsigned*)(xout_bf + (size_t)row * DIM + col) =
                            (unsigned)bv | (pb << 16);
                }
                s += v * waS[nf];
                d += v * waD[nf];
            }
            if (do_dots) {
                #pragma unroll
                for (int off = 1; off < 16; off <<= 1) {
                    s += __shfl_xor(s, off);
                    d += __shfl_xor(d, off);
                }
                if (l16 == 0) {
                    const int rl = waveM * 64 + mf * 16 + rsub + j;
                    psS[waveN][rl] = s;
                    psD[waveN][rl] = d;
                }
            }
        }
    }
    if (do_dots) {
        __syncthreads();
        if (tid < 128) {
            const int row = mbase + tid;
            a_src_next[row] = psS[0][tid] + psS[1][tid];
            a_dst_next[row] = psD[0][tid] + psD[1][tid] + ba_next[0];
        }
    }
}

// ---------------------------------------------------------------------------
extern "C" void kernel_launch(void* const* d_in, const int* in_sizes, int n_in,
                              void* d_out, int out_size, void* d_ws, size_t ws_size,
                              hipStream_t stream) {
    const int*   edge = (const int*)d_in[0];       // [2, E]
    const float* ue   = (const float*)d_in[1];
    const float* ie   = (const float*)d_in[2];
    const float* Wa   = (const float*)d_in[3];     // [3, 256, 1]
    const float* ba   = (const float*)d_in[4];     // [3, 1]
    const float* Wg   = (const float*)d_in[5];     // [3, 256, 128]
    const float* bg   = (const float*)d_in[6];     // [3, 128]

    const int* src = edge;
    const int* dst = edge + NEDGES;

    float* x = (float*)d_out;                      // final f32 output

    // ---- workspace layout ----
    unsigned short* xb0  = (unsigned short*)d_ws;            // NPAD*128 bf16
    unsigned short* xb1  = xb0 + (size_t)NPAD * DIM;         // NPAD*128 bf16
    unsigned short* bfr  = xb1 + (size_t)NPAD * DIM;         // 3*32768 bf16
    float* aSA        = (float*)(bfr + NLAYERS * 32768);     // NPAD f
    float* aDA        = aSA + NPAD;                          // NPAD f
    float* aSB        = aDA + NPAD;                          // NPAD f
    float* aDB        = aSB + NPAD;                          // NPAD f
    int*   row_start  = (int*)(aDB + NPAD);                  // NPAD+256 i
    int*   csr_src    = row_start + NPAD + 256;              // NEDGES i
    unsigned* pairs   = (unsigned*)(csr_src + NEDGES);       // NEDGES u
    unsigned* counts  = pairs + NEDGES;                      // NBLK*NBUCK u
    unsigned* bbase   = counts + (size_t)NBLK * NBUCK;       // NBUCK+1 u

    concat_kernel<<<(NNODES * DIM / 4 + 255) / 256, 256, 0, stream>>>(ue, ie, xb0);
    wg_conv_kernel<<<(NLAYERS * 4096 + 255) / 256, 256, 0, stream>>>(Wg, bfr);

    // ---- binned CSR build ----
    bin_count_kernel<<<NBLK, 256, 0, stream>>>(dst, counts);
    prefix_kernel<<<1, 1024, 0, stream>>>(counts, bbase);
    bin_scatter_kernel<<<NBLK, 256, 0, stream>>>(src, dst, counts, bbase, pairs);
    bucket_csr_kernel<<<NBUCK, 256, 0, stream>>>(pairs, bbase, row_start, csr_src);

    // layer-0 attention dots
    node_dots_kernel<<<(NNODES * 64 + 255) / 256, 256, 0, stream>>>(
        xb0, Wa, ba, aSA, aDA);

    const int blocks = (NNODES + 127) / 128;                 // 782

    // layer 0: xb0 -> xb1, dots for layer 1 into B
    layer_kernel<<<blocks, 256, 0, stream>>>(
        xb0, row_start, csr_src, aSA, aDA,
        bfr, bg, Wa + 256, ba + 1, aSB, aDB,
        x, xb1, 0, 1);
    // layer 1: xb1 -> xb0, dots for layer 2 into A
    layer_kernel<<<blocks, 256, 0, stream>>>(
        xb1, row_start, csr_src, aSB, aDB,
        bfr + 32768, bg + DIM, Wa + 512, ba + 2, aSA, aDA,
        x, xb0, 0, 1);
    // layer 2: xb0 -> f32 output, no dots
    layer_kernel<<<blocks, 256, 0, stream>>>(
        xb0, row_start, csr_src, aSA, aDA,
        bfr + 65536, bg + 2 * DIM, Wa, ba, aSB, aDB,
        x, xb1, 1, 0);
}

// Round 9
// 249.646 us; speedup vs baseline: 1.2225x; 1.2225x over previous
//
#include <hip/hip_runtime.h>
#include <cstddef>
#include <cstdint>

#define NUSERS 50000
#define NITEMS 50000
#define NNODES 100000
#define DIM    128
#define NLAYERS 3
#define NEDGES 600000
#define NPAD 100096           // 391*256  (>=96 rows of slack past NNODES)

#define EBLK  8192            // edges per binning block
#define NBLK  74              // ceil(600000/8192)
#define NBUCK 782             // ceil(100000/128), bucket = dst>>7

typedef __attribute__((ext_vector_type(8))) short short8;
typedef __attribute__((ext_vector_type(4))) float f32x4;

__device__ __forceinline__ float bf_lo(unsigned u) { return __uint_as_float(u << 16); }
__device__ __forceinline__ float bf_hi(unsigned u) { return __uint_as_float(u & 0xffff0000u); }
__device__ __forceinline__ unsigned short f2bf(float f) {      // round-nearest-even
    unsigned b = __float_as_uint(f);
    return (unsigned short)((b + 0x7fffu + ((b >> 16) & 1u)) >> 16);
}

// async global->LDS 16B per lane; dst must be wave-uniform base (HW adds lane*16)
__device__ __forceinline__ void async16(const void* g, void* l) {
    __builtin_amdgcn_global_load_lds(
        (const __attribute__((address_space(1))) unsigned int*)(uintptr_t)g,
        (__attribute__((address_space(3))) unsigned int*)(unsigned int)(uintptr_t)l,
        16, 0, 0);
}

// ---------------------------------------------------------------------------
// concat + layer-0 attention dots, quarter-wave per node (16 lanes, 32B/lane)
// ---------------------------------------------------------------------------
__global__ __launch_bounds__(256) void concat_dots_kernel(
        const float* __restrict__ ue, const float* __restrict__ ie,
        const float* __restrict__ Wa, const float* __restrict__ ba,
        unsigned short* __restrict__ xb,
        float* __restrict__ a_src, float* __restrict__ a_dst) {
    const int n = blockIdx.x * 16 + (threadIdx.x >> 4);
    if (n >= NNODES) return;
    const int sub = threadIdx.x & 15;
    const float* r = (n < NUSERS) ? (ue + (size_t)n * DIM)
                                  : (ie + (size_t)(n - NUSERS) * DIM);
    const float4 v0 = *(const float4*)(r + sub * 8);
    const float4 v1 = *(const float4*)(r + sub * 8 + 4);
    const float4 wl0 = *(const float4*)(Wa + sub * 8);
    const float4 wl1 = *(const float4*)(Wa + sub * 8 + 4);
    const float4 wh0 = *(const float4*)(Wa + DIM + sub * 8);
    const float4 wh1 = *(const float4*)(Wa + DIM + sub * 8 + 4);

    uint4 o;
    o.x = ((unsigned)f2bf(v0.y) << 16) | (unsigned)f2bf(v0.x);
    o.y = ((unsigned)f2bf(v0.w) << 16) | (unsigned)f2bf(v0.z);
    o.z = ((unsigned)f2bf(v1.y) << 16) | (unsigned)f2bf(v1.x);
    o.w = ((unsigned)f2bf(v1.w) << 16) | (unsigned)f2bf(v1.z);
    *(uint4*)(xb + (size_t)n * DIM + sub * 8) = o;

    float ps = v0.x * wl0.x + v0.y * wl0.y + v0.z * wl0.z + v0.w * wl0.w
             + v1.x * wl1.x + v1.y * wl1.y + v1.z * wl1.z + v1.w * wl1.w;
    float pd = v0.x * wh0.x + v0.y * wh0.y + v0.z * wh0.z + v0.w * wh0.w
             + v1.x * wh1.x + v1.y * wh1.y + v1.z * wh1.z + v1.w * wh1.w;
    #pragma unroll
    for (int off = 1; off < 16; off <<= 1) {
        ps += __shfl_xor(ps, off);
        pd += __shfl_xor(pd, off);
    }
    if (sub == 0) { a_src[n] = ps; a_dst[n] = pd + ba[0]; }
}

// ---------------------------------------------------------------------------
// Bf[l][nb][ks][nf][lane][8] = Wg[l][k][col] in MFMA B-fragment order
// ---------------------------------------------------------------------------
__global__ void wg_conv_kernel(const float* __restrict__ Wg,
                               unsigned short* __restrict__ Bf) {
    const int tid = blockIdx.x * blockDim.x + threadIdx.x;   // one per 8 elems
    if (tid >= NLAYERS * 4096) return;
    const int l    = tid >> 12;
    const int slot = tid & 4095;
    const int lane = slot & 63;
    const int t2   = slot >> 6;
    const int nf   = t2 & 3;
    const int t3   = t2 >> 2;
    const int ks   = t3 & 7;
    const int nb   = t3 >> 3;
    const int col  = nb * 64 + nf * 16 + (lane & 15);
    const int k0   = ks * 32 + (lane >> 4) * 8;
    const float* wsrc = Wg + (size_t)l * 256 * DIM;
    unsigned short o[8];
    #pragma unroll
    for (int j = 0; j < 8; ++j) o[j] = f2bf(wsrc[(size_t)(k0 + j) * DIM + col]);
    *(short8*)(Bf + (size_t)tid * 8) = *(short8*)o;
}

// ---------------------------------------------------------------------------
// binned CSR build
// ---------------------------------------------------------------------------
__global__ __launch_bounds__(256) void bin_count_kernel(
        const int* __restrict__ dst, unsigned* __restrict__ counts) {
    __shared__ unsigned hist[NBUCK];
    for (int i = threadIdx.x; i < NBUCK; i += 256) hist[i] = 0;
    __syncthreads();
    const int base = blockIdx.x * EBLK;
    const int end  = (base + EBLK < NEDGES) ? base + EBLK : NEDGES;
    for (int e = base + threadIdx.x; e < end; e += 256)
        atomicAdd(&hist[dst[e] >> 7], 1u);
    __syncthreads();
    for (int i = threadIdx.x; i < NBUCK; i += 256)
        counts[(size_t)blockIdx.x * NBUCK + i] = hist[i];
}

// merged: per-bucket column prefix over blocks + exclusive scan of totals
__global__ __launch_bounds__(1024) void prefix_kernel(
        unsigned* __restrict__ counts, unsigned* __restrict__ bucketbase) {
    const int b = threadIdx.x;
    unsigned tot = 0;
    if (b < NBUCK) {
        for (int i = 0; i < NBLK; ++i) {
            const unsigned c = counts[(size_t)i * NBUCK + b];
            counts[(size_t)i * NBUCK + b] = tot;
            tot += c;
        }
    }
    const int lane = b & 63, w = b >> 6;
    unsigned s = tot;
    #pragma unroll
    for (int o = 1; o < 64; o <<= 1) {
        unsigned t = (unsigned)__shfl_up((int)s, o);
        if (lane >= o) s += t;
    }
    __shared__ unsigned wsum[16];
    if (lane == 63) wsum[w] = s;
    __syncthreads();
    unsigned add = 0;
    #pragma unroll
    for (int j = 0; j < 15; ++j) if (w > j) add += wsum[j];
    if (b < NBUCK) bucketbase[b] = s + add - tot;
    if (b == NBUCK - 1) bucketbase[NBUCK] = s + add;   // == NEDGES
}

__global__ __launch_bounds__(256) void bin_scatter_kernel(
        const int* __restrict__ src, const int* __restrict__ dst,
        const unsigned* __restrict__ counts, const unsigned* __restrict__ bucketbase,
        unsigned* __restrict__ pairs) {
    __shared__ unsigned off[NBUCK];
    for (int i = threadIdx.x; i < NBUCK; i += 256)
        off[i] = bucketbase[i] + counts[(size_t)blockIdx.x * NBUCK + i];
    __syncthreads();
    const int base = blockIdx.x * EBLK;
    const int end  = (base + EBLK < NEDGES) ? base + EBLK : NEDGES;
    for (int e = base + threadIdx.x; e < end; e += 256) {
        const int d = dst[e];
        const unsigned pos = atomicAdd(&off[d >> 7], 1u);
        pairs[pos] = ((unsigned)(d & 127) << 17) | (unsigned)src[e];
    }
}

__global__ __launch_bounds__(256) void bucket_csr_kernel(
        const unsigned* __restrict__ pairs, const unsigned* __restrict__ bucketbase,
        int* __restrict__ row_start, int* __restrict__ csr_src) {
    __shared__ unsigned deg[128], rs[128], fill[128];
    const int b = blockIdx.x;
    const unsigned seg0 = bucketbase[b], seg1 = bucketbase[b + 1];
    const int t = threadIdx.x;
    if (t < 128) deg[t] = 0;
    __syncthreads();
    for (unsigned i = seg0 + t; i < seg1; i += 256)
        atomicAdd(&deg[pairs[i] >> 17], 1u);
    __syncthreads();
    if (t < 128) rs[t] = deg[t];
    __syncthreads();
    #pragma unroll
    for (int o = 1; o < 128; o <<= 1) {           // Hillis-Steele inclusive
        unsigned tmp = 0;
        if (t < 128 && t >= o) tmp = rs[t - o];
        __syncthreads();
        if (t < 128) rs[t] += tmp;
        __syncthreads();
    }
    if (t < 128) {
        const unsigned excl = rs[t] - deg[t];
        fill[t] = excl;
        const int node = b * 128 + t;
        if (node < NNODES) row_start[node] = (int)(seg0 + excl);
    }
    __syncthreads();
    for (unsigned i = seg0 + t; i < seg1; i += 256) {
        const unsigned p = pairs[i];
        const unsigned r = atomicAdd(&fill[p >> 17], 1u);
        csr_src[seg0 + r] = (int)(p & 0x1ffffu);
    }
    if (b == 0 && t == 0) row_start[NNODES] = NEDGES;
}

// ---------------------------------------------------------------------------
// pull aggregation, quarter-wave (16 lanes = one node, 16B/lane), fused att
// ---------------------------------------------------------------------------
__global__ __launch_bounds__(256) void pull_agg_kernel(
        const int* __restrict__ row_start, const int* __restrict__ csr_src,
        const float* __restrict__ a_src, const float* __restrict__ a_dst,
        const unsigned short* __restrict__ xb, unsigned short* __restrict__ aggb) {
    const int n = blockIdx.x * 16 + (threadIdx.x >> 4);
    if (n >= NNODES) return;
    const int lane = threadIdx.x & 63;
    const int sub  = lane & 15;        // position within quarter
    const int qb   = lane & 48;        // quarter base lane
    const int beg = row_start[n], end = row_start[n + 1];
    const float adst = a_dst[n];

    float a0 = 0, a1 = 0, a2 = 0, a3 = 0, a4 = 0, a5 = 0, a6 = 0, a7 = 0;

    for (int base = beg; base < end; base += 16) {
        const int rem = end - base;
        const int cnt = rem < 16 ? rem : 16;
        int   idx_l = 0;
        float att_l = 0.0f;
        if (sub < cnt) {
            idx_l = csr_src[base + sub];
            att_l = 1.0f / (1.0f + __expf(-(a_src[idx_l] + adst)));
        }
        int i = 0;
        for (; i + 3 < cnt; i += 4) {
            const int   s0 = __shfl(idx_l, qb + i);
            const int   s1 = __shfl(idx_l, qb + i + 1);
            const int   s2 = __shfl(idx_l, qb + i + 2);
            const int   s3 = __shfl(idx_l, qb + i + 3);
            const float w0 = __shfl(att_l, qb + i);
            const float w1 = __shfl(att_l, qb + i + 1);
            const float w2 = __shfl(att_l, qb + i + 2);
            const float w3 = __shfl(att_l, qb + i + 3);
            const uint4 u0 = *(const uint4*)(xb + (size_t)s0 * DIM + sub * 8);
            const uint4 u1 = *(const uint4*)(xb + (size_t)s1 * DIM + sub * 8);
            const uint4 u2 = *(const uint4*)(xb + (size_t)s2 * DIM + sub * 8);
            const uint4 u3 = *(const uint4*)(xb + (size_t)s3 * DIM + sub * 8);
            a0 += bf_lo(u0.x) * w0 + bf_lo(u1.x) * w1 + bf_lo(u2.x) * w2 + bf_lo(u3.x) * w3;
            a1 += bf_hi(u0.x) * w0 + bf_hi(u1.x) * w1 + bf_hi(u2.x) * w2 + bf_hi(u3.x) * w3;
            a2 += bf_lo(u0.y) * w0 + bf_lo(u1.y) * w1 + bf_lo(u2.y) * w2 + bf_lo(u3.y) * w3;
            a3 += bf_hi(u0.y) * w0 + bf_hi(u1.y) * w1 + bf_hi(u2.y) * w2 + bf_hi(u3.y) * w3;
            a4 += bf_lo(u0.z) * w0 + bf_lo(u1.z) * w1 + bf_lo(u2.z) * w2 + bf_lo(u3.z) * w3;
            a5 += bf_hi(u0.z) * w0 + bf_hi(u1.z) * w1 + bf_hi(u2.z) * w2 + bf_hi(u3.z) * w3;
            a6 += bf_lo(u0.w) * w0 + bf_lo(u1.w) * w1 + bf_lo(u2.w) * w2 + bf_lo(u3.w) * w3;
            a7 += bf_hi(u0.w) * w0 + bf_hi(u1.w) * w1 + bf_hi(u2.w) * w2 + bf_hi(u3.w) * w3;
        }
        for (; i < cnt; ++i) {
            const int   s = __shfl(idx_l, qb + i);
            const float w = __shfl(att_l, qb + i);
            const uint4 u = *(const uint4*)(xb + (size_t)s * DIM + sub * 8);
            a0 += bf_lo(u.x) * w;  a1 += bf_hi(u.x) * w;
            a2 += bf_lo(u.y) * w;  a3 += bf_hi(u.y) * w;
            a4 += bf_lo(u.z) * w;  a5 += bf_hi(u.z) * w;
            a6 += bf_lo(u.w) * w;  a7 += bf_hi(u.w) * w;
        }
    }

    uint4 o;
    o.x = ((unsigned)f2bf(a1) << 16) | (unsigned)f2bf(a0);
    o.y = ((unsigned)f2bf(a3) << 16) | (unsigned)f2bf(a2);
    o.z = ((unsigned)f2bf(a5) << 16) | (unsigned)f2bf(a4);
    o.w = ((unsigned)f2bf(a7) << 16) | (unsigned)f2bf(a6);
    *(uint4*)(aggb + (size_t)n * DIM + sub * 8) = o;
}

// ---------------------------------------------------------------------------
// x_new = relu([x || agg] @ Wg + bg) via bf16 MFMA (async LDS A-staging),
// with next-layer attention dots fused into the epilogue.
// ---------------------------------------------------------------------------
__global__ __launch_bounds__(256) void gemm_mfma_kernel(
        unsigned short* __restrict__ xb, const unsigned short* __restrict__ aggb,
        const unsigned short* __restrict__ bfr, const float* __restrict__ bg,
        const float* __restrict__ wa_next, const float* __restrict__ ba_next,
        float* __restrict__ a_src, float* __restrict__ a_dst,
        float* __restrict__ xout_f32, int write_f32, int do_dots) {
    __shared__ unsigned short At[2][128 * 128];     // 64 KB
    __shared__ float psS[2][128], psD[2][128];      // 2 KB

    const int tid  = threadIdx.x;
    const int lane = tid & 63;
    const int wid  = tid >> 6;
    const int mbase = blockIdx.x * 128;

    #pragma unroll
    for (int h = 0; h < 2; ++h) {
        const unsigned short* s = h ? aggb : xb;
        #pragma unroll
        for (int i = 0; i < 8; ++i) {
            const int lrow = i * 16 + wid * 4 + (lane >> 4);       // 0..127
            const int c    = (lane & 15) ^ (lrow & 7);             // src chunk
            async16(s + (size_t)(mbase + lrow) * DIM + c * 8,
                    &At[h][(i * 16 + wid * 4) * 128]);             // uniform base
        }
    }

    const int waveM = wid >> 1, waveN = wid & 1;
    const int l16 = lane & 15, kq = lane >> 4;
    const unsigned short* bfw = bfr + (size_t)(waveN * 8) * 4 * 64 * 8;

    f32x4 acc[4][4] = {};
    short8 bcur[4], bnxt[4];

    asm volatile("s_waitcnt vmcnt(8)" ::: "memory");
    __builtin_amdgcn_s_barrier();

    #pragma unroll
    for (int nf = 0; nf < 4; ++nf)
        bcur[nf] = *(const short8*)(bfw + ((size_t)(0 * 4 + nf) * 64 + lane) * 8);

    #pragma unroll
    for (int ks = 0; ks < 8; ++ks) {
        if (ks == 4) {
            asm volatile("s_waitcnt vmcnt(0)" ::: "memory");
            __builtin_amdgcn_s_barrier();
        }
        if (ks < 7) {
            #pragma unroll
            for (int nf = 0; nf < 4; ++nf)
                bnxt[nf] = *(const short8*)(bfw + ((size_t)((ks + 1) * 4 + nf) * 64 + lane) * 8);
        }
        const int h = ks >> 2, ksl = ks & 3;
        short8 a[4];
        #pragma unroll
        for (int mf = 0; mf < 4; ++mf) {
            const int row   = waveM * 64 + mf * 16 + l16;
            const int chunk = (ksl * 4 + kq) ^ (row & 7);
            a[mf] = *(const short8*)&At[h][row * 128 + chunk * 8];
        }
        #pragma unroll
        for (int mf = 0; mf < 4; ++mf)
            #pragma unroll
            for (int nf = 0; nf < 4; ++nf)
                acc[mf][nf] = __builtin_amdgcn_mfma_f32_16x16x32_bf16(
                    a[mf], bcur[nf], acc[mf][nf], 0, 0, 0);
        if (ks < 7) {
            #pragma unroll
            for (int nf = 0; nf < 4; ++nf) bcur[nf] = bnxt[nf];
        }
    }

    // epilogue: bias + relu store (+ fused next-layer dots)
    const int rsub = kq * 4;
    float waS[4] = {0, 0, 0, 0}, waD[4] = {0, 0, 0, 0}, bias[4];
    #pragma unroll
    for (int nf = 0; nf < 4; ++nf) {
        const int col = waveN * 64 + nf * 16 + l16;
        bias[nf] = bg[col];
        if (do_dots) { waS[nf] = wa_next[col]; waD[nf] = wa_next[DIM + col]; }
    }
    #pragma unroll
    for (int mf = 0; mf < 4; ++mf) {
        #pragma unroll
        for (int j = 0; j < 4; ++j) {
            const int row = mbase + waveM * 64 + mf * 16 + rsub + j;
            float s = 0.0f, d = 0.0f;
            #pragma unroll
            for (int nf = 0; nf < 4; ++nf) {
                const int col = waveN * 64 + nf * 16 + l16;
                const float v = fmaxf(acc[mf][nf][j] + bias[nf], 0.0f);
                if (write_f32) {
                    if (row < NNODES) xout_f32[(size_t)row * DIM + col] = v;
                } else {
                    const unsigned short bv = f2bf(v);
                    const unsigned pb = (unsigned)(unsigned short)__shfl_xor((int)bv, 1);
                    if (!(l16 & 1) && row < NNODES)
                        *(unsigned*)(xb + (size_t)row * DIM + col) =
                            (unsigned)bv | (pb << 16);
                }
                s += v * waS[nf];
                d += v * waD[nf];
            }
            if (do_dots) {
                #pragma unroll
                for (int off = 1; off < 16; off <<= 1) {
                    s += __shfl_xor(s, off);
                    d += __shfl_xor(d, off);
                }
                if (l16 == 0) {
                    const int rl = waveM * 64 + mf * 16 + rsub + j;
                    psS[waveN][rl] = s;
                    psD[waveN][rl] = d;
                }
            }
        }
    }
    if (do_dots) {
        __syncthreads();
        if (tid < 128) {
            const int row = mbase + tid;
            if (row < NNODES) {
                a_src[row] = psS[0][tid] + psS[1][tid];
                a_dst[row] = psD[0][tid] + psD[1][tid] + ba_next[0];
            }
        }
    }
}

// ---------------------------------------------------------------------------
extern "C" void kernel_launch(void* const* d_in, const int* in_sizes, int n_in,
                              void* d_out, int out_size, void* d_ws, size_t ws_size,
                              hipStream_t stream) {
    const int*   edge = (const int*)d_in[0];       // [2, E]
    const float* ue   = (const float*)d_in[1];
    const float* ie   = (const float*)d_in[2];
    const float* Wa   = (const float*)d_in[3];     // [3, 256, 1]
    const float* ba   = (const float*)d_in[4];     // [3, 1]
    const float* Wg   = (const float*)d_in[5];     // [3, 256, 128]
    const float* bg   = (const float*)d_in[6];     // [3, 128]

    const int* src = edge;
    const int* dst = edge + NEDGES;

    float* x = (float*)d_out;                      // final f32 output

    // ---- workspace layout ----
    unsigned short* xb   = (unsigned short*)d_ws;            // NPAD*128 bf16
    unsigned short* aggb = xb + (size_t)NPAD * DIM;          // NPAD*128 bf16
    unsigned short* bfr  = aggb + (size_t)NPAD * DIM;        // 3*32768 bf16
    float* a_src      = (float*)(bfr + NLAYERS * 32768);     // NPAD f
    float* a_dst      = a_src + NPAD;                        // NPAD f
    int*   row_start  = (int*)(a_dst + NPAD);                // NPAD+256 i
    int*   csr_src    = row_start + NPAD + 256;              // NEDGES i
    unsigned* pairs   = (unsigned*)(csr_src + NEDGES);       // NEDGES u
    unsigned* counts  = pairs + NEDGES;                      // NBLK*NBUCK u
    unsigned* bbase   = counts + (size_t)NBLK * NBUCK;       // NBUCK+1 u

    concat_dots_kernel<<<(NNODES + 15) / 16, 256, 0, stream>>>(
        ue, ie, Wa, ba, xb, a_src, a_dst);
    wg_conv_kernel<<<(NLAYERS * 4096 + 255) / 256, 256, 0, stream>>>(Wg, bfr);

    // ---- binned CSR build ----
    bin_count_kernel<<<NBLK, 256, 0, stream>>>(dst, counts);
    prefix_kernel<<<1, 1024, 0, stream>>>(counts, bbase);
    bin_scatter_kernel<<<NBLK, 256, 0, stream>>>(src, dst, counts, bbase, pairs);
    bucket_csr_kernel<<<NBUCK, 256, 0, stream>>>(pairs, bbase, row_start, csr_src);

    const int gemm_blocks = (NNODES + 127) / 128;            // 782
    const int pull_blocks = (NNODES + 15) / 16;              // 6250
    for (int l = 0; l < NLAYERS; ++l) {
        pull_agg_kernel<<<pull_blocks, 256, 0, stream>>>(
            row_start, csr_src, a_src, a_dst, xb, aggb);
        const int last = (l == NLAYERS - 1);
        gemm_mfma_kernel<<<gemm_blocks, 256, 0, stream>>>(
            xb, aggb, bfr + (size_t)l * 32768, bg + (size_t)l * DIM,
            Wa + (size_t)(l + 1 < NLAYERS ? l + 1 : 0) * 256,
            ba + (l + 1 < NLAYERS ? l + 1 : 0),
            a_src, a_dst, x, last ? 1 : 0, last ? 0 : 1);
    }
}

// Round 10
// 230.692 us; speedup vs baseline: 1.3229x; 1.0822x over previous
//
#include <hip/hip_runtime.h>
#include <cstddef>
#include <cstdint>

#define NUSERS 50000
#define NITEMS 50000
#define NNODES 100000
#define DIM    128
#define NLAYERS 3
#define NEDGES 600000
#define NPAD 100096           // 391*256  (>=96 rows of slack past NNODES)

#define EBLK  8192            // edges per binning block
#define NBLK  74              // ceil(600000/8192)
#define NBUCK 782             // ceil(100000/128), bucket = dst>>7

typedef __attribute__((ext_vector_type(8))) short short8;
typedef __attribute__((ext_vector_type(4))) float f32x4;

__device__ __forceinline__ float bf_lo(unsigned u) { return __uint_as_float(u << 16); }
__device__ __forceinline__ float bf_hi(unsigned u) { return __uint_as_float(u & 0xffff0000u); }
__device__ __forceinline__ unsigned short f2bf(float f) {      // round-nearest-even
    unsigned b = __float_as_uint(f);
    return (unsigned short)((b + 0x7fffu + ((b >> 16) & 1u)) >> 16);
}

// async global->LDS 16B per lane; dst must be wave-uniform base (HW adds lane*16)
__device__ __forceinline__ void async16(const void* g, void* l) {
    __builtin_amdgcn_global_load_lds(
        (const __attribute__((address_space(1))) unsigned int*)(uintptr_t)g,
        (__attribute__((address_space(3))) unsigned int*)(unsigned int)(uintptr_t)l,
        16, 0, 0);
}

// ---------------------------------------------------------------------------
// concat + layer-0 attention dots, quarter-wave per node (16 lanes, 32B/lane)
// ---------------------------------------------------------------------------
__global__ __launch_bounds__(256) void concat_dots_kernel(
        const float* __restrict__ ue, const float* __restrict__ ie,
        const float* __restrict__ Wa, const float* __restrict__ ba,
        unsigned short* __restrict__ xb,
        float* __restrict__ a_src, float* __restrict__ a_dst) {
    const int n = blockIdx.x * 16 + (threadIdx.x >> 4);
    if (n >= NNODES) return;
    const int sub = threadIdx.x & 15;
    const float* r = (n < NUSERS) ? (ue + (size_t)n * DIM)
                                  : (ie + (size_t)(n - NUSERS) * DIM);
    const float4 v0 = *(const float4*)(r + sub * 8);
    const float4 v1 = *(const float4*)(r + sub * 8 + 4);
    const float4 wl0 = *(const float4*)(Wa + sub * 8);
    const float4 wl1 = *(const float4*)(Wa + sub * 8 + 4);
    const float4 wh0 = *(const float4*)(Wa + DIM + sub * 8);
    const float4 wh1 = *(const float4*)(Wa + DIM + sub * 8 + 4);

    uint4 o;
    o.x = ((unsigned)f2bf(v0.y) << 16) | (unsigned)f2bf(v0.x);
    o.y = ((unsigned)f2bf(v0.w) << 16) | (unsigned)f2bf(v0.z);
    o.z = ((unsigned)f2bf(v1.y) << 16) | (unsigned)f2bf(v1.x);
    o.w = ((unsigned)f2bf(v1.w) << 16) | (unsigned)f2bf(v1.z);
    *(uint4*)(xb + (size_t)n * DIM + sub * 8) = o;

    float ps = v0.x * wl0.x + v0.y * wl0.y + v0.z * wl0.z + v0.w * wl0.w
             + v1.x * wl1.x + v1.y * wl1.y + v1.z * wl1.z + v1.w * wl1.w;
    float pd = v0.x * wh0.x + v0.y * wh0.y + v0.z * wh0.z + v0.w * wh0.w
             + v1.x * wh1.x + v1.y * wh1.y + v1.z * wh1.z + v1.w * wh1.w;
    #pragma unroll
    for (int off = 1; off < 16; off <<= 1) {
        ps += __shfl_xor(ps, off);
        pd += __shfl_xor(pd, off);
    }
    if (sub == 0) { a_src[n] = ps; a_dst[n] = pd + ba[0]; }
}

// ---------------------------------------------------------------------------
// Bf[l][nb][ks][nf][lane][8] = Wg[l][k][col] in MFMA B-fragment order
// ---------------------------------------------------------------------------
__global__ void wg_conv_kernel(const float* __restrict__ Wg,
                               unsigned short* __restrict__ Bf) {
    const int tid = blockIdx.x * blockDim.x + threadIdx.x;   // one per 8 elems
    if (tid >= NLAYERS * 4096) return;
    const int l    = tid >> 12;
    const int slot = tid & 4095;
    const int lane = slot & 63;
    const int t2   = slot >> 6;
    const int nf   = t2 & 3;
    const int t3   = t2 >> 2;
    const int ks   = t3 & 7;
    const int nb   = t3 >> 3;
    const int col  = nb * 64 + nf * 16 + (lane & 15);
    const int k0   = ks * 32 + (lane >> 4) * 8;
    const float* wsrc = Wg + (size_t)l * 256 * DIM;
    unsigned short o[8];
    #pragma unroll
    for (int j = 0; j < 8; ++j) o[j] = f2bf(wsrc[(size_t)(k0 + j) * DIM + col]);
    *(short8*)(Bf + (size_t)tid * 8) = *(short8*)o;
}

// ---------------------------------------------------------------------------
// binned CSR build
// ---------------------------------------------------------------------------
__global__ __launch_bounds__(256) void bin_count_kernel(
        const int* __restrict__ dst, unsigned* __restrict__ counts) {
    __shared__ unsigned hist[NBUCK];
    for (int i = threadIdx.x; i < NBUCK; i += 256) hist[i] = 0;
    __syncthreads();
    const int base = blockIdx.x * EBLK;
    const int end  = (base + EBLK < NEDGES) ? base + EBLK : NEDGES;
    for (int e = base + threadIdx.x; e < end; e += 256)
        atomicAdd(&hist[dst[e] >> 7], 1u);
    __syncthreads();
    for (int i = threadIdx.x; i < NBUCK; i += 256)
        counts[(size_t)blockIdx.x * NBUCK + i] = hist[i];
}

// merged: per-bucket column prefix over blocks + exclusive scan of totals
__global__ __launch_bounds__(1024) void prefix_kernel(
        unsigned* __restrict__ counts, unsigned* __restrict__ bucketbase) {
    const int b = threadIdx.x;
    unsigned tot = 0;
    if (b < NBUCK) {
        for (int i = 0; i < NBLK; ++i) {
            const unsigned c = counts[(size_t)i * NBUCK + b];
            counts[(size_t)i * NBUCK + b] = tot;
            tot += c;
        }
    }
    const int lane = b & 63, w = b >> 6;
    unsigned s = tot;
    #pragma unroll
    for (int o = 1; o < 64; o <<= 1) {
        unsigned t = (unsigned)__shfl_up((int)s, o);
        if (lane >= o) s += t;
    }
    __shared__ unsigned wsum[16];
    if (lane == 63) wsum[w] = s;
    __syncthreads();
    unsigned add = 0;
    #pragma unroll
    for (int j = 0; j < 15; ++j) if (w > j) add += wsum[j];
    if (b < NBUCK) bucketbase[b] = s + add - tot;
    if (b == NBUCK - 1) bucketbase[NBUCK] = s + add;   // == NEDGES
}

__global__ __launch_bounds__(256) void bin_scatter_kernel(
        const int* __restrict__ src, const int* __restrict__ dst,
        const unsigned* __restrict__ counts, const unsigned* __restrict__ bucketbase,
        unsigned* __restrict__ pairs) {
    __shared__ unsigned off[NBUCK];
    for (int i = threadIdx.x; i < NBUCK; i += 256)
        off[i] = bucketbase[i] + counts[(size_t)blockIdx.x * NBUCK + i];
    __syncthreads();
    const int base = blockIdx.x * EBLK;
    const int end  = (base + EBLK < NEDGES) ? base + EBLK : NEDGES;
    for (int e = base + threadIdx.x; e < end; e += 256) {
        const int d = dst[e];
        const unsigned pos = atomicAdd(&off[d >> 7], 1u);
        pairs[pos] = ((unsigned)(d & 127) << 17) | (unsigned)src[e];
    }
}

__global__ __launch_bounds__(256) void bucket_csr_kernel(
        const unsigned* __restrict__ pairs, const unsigned* __restrict__ bucketbase,
        int* __restrict__ row_start, int* __restrict__ csr_src) {
    __shared__ unsigned deg[128], rs[128], fill[128];
    const int b = blockIdx.x;
    const unsigned seg0 = bucketbase[b], seg1 = bucketbase[b + 1];
    const int t = threadIdx.x;
    if (t < 128) deg[t] = 0;
    __syncthreads();
    for (unsigned i = seg0 + t; i < seg1; i += 256)
        atomicAdd(&deg[pairs[i] >> 17], 1u);
    __syncthreads();
    if (t < 128) rs[t] = deg[t];
    __syncthreads();
    #pragma unroll
    for (int o = 1; o < 128; o <<= 1) {           // Hillis-Steele inclusive
        unsigned tmp = 0;
        if (t < 128 && t >= o) tmp = rs[t - o];
        __syncthreads();
        if (t < 128) rs[t] += tmp;
        __syncthreads();
    }
    if (t < 128) {
        const unsigned excl = rs[t] - deg[t];
        fill[t] = excl;
        const int node = b * 128 + t;
        if (node < NNODES) row_start[node] = (int)(seg0 + excl);
    }
    __syncthreads();
    for (unsigned i = seg0 + t; i < seg1; i += 256) {
        const unsigned p = pairs[i];
        const unsigned r = atomicAdd(&fill[p >> 17], 1u);
        csr_src[seg0 + r] = (int)(p & 0x1ffffu);
    }
    if (b == 0 && t == 0) row_start[NNODES] = NEDGES;
}

// ---------------------------------------------------------------------------
// pull aggregation, quarter-wave (16 lanes = one node, 16B/lane), fused att
// ---------------------------------------------------------------------------
__global__ __launch_bounds__(256) void pull_agg_kernel(
        const int* __restrict__ row_start, const int* __restrict__ csr_src,
        const float* __restrict__ a_src, const float* __restrict__ a_dst,
        const unsigned short* __restrict__ xb, unsigned short* __restrict__ aggb) {
    const int n = blockIdx.x * 16 + (threadIdx.x >> 4);
    if (n >= NNODES) return;
    const int lane = threadIdx.x & 63;
    const int sub  = lane & 15;        // position within quarter
    const int qb   = lane & 48;        // quarter base lane
    const int beg = row_start[n], end = row_start[n + 1];
    const float adst = a_dst[n];

    float a0 = 0, a1 = 0, a2 = 0, a3 = 0, a4 = 0, a5 = 0, a6 = 0, a7 = 0;

    for (int base = beg; base < end; base += 16) {
        const int rem = end - base;
        const int cnt = rem < 16 ? rem : 16;
        int   idx_l = 0;
        float att_l = 0.0f;
        if (sub < cnt) {
            idx_l = csr_src[base + sub];
            att_l = 1.0f / (1.0f + __expf(-(a_src[idx_l] + adst)));
        }
        int i = 0;
        for (; i + 3 < cnt; i += 4) {
            const int   s0 = __shfl(idx_l, qb + i);
            const int   s1 = __shfl(idx_l, qb + i + 1);
            const int   s2 = __shfl(idx_l, qb + i + 2);
            const int   s3 = __shfl(idx_l, qb + i + 3);
            const float w0 = __shfl(att_l, qb + i);
            const float w1 = __shfl(att_l, qb + i + 1);
            const float w2 = __shfl(att_l, qb + i + 2);
            const float w3 = __shfl(att_l, qb + i + 3);
            const uint4 u0 = *(const uint4*)(xb + (size_t)s0 * DIM + sub * 8);
            const uint4 u1 = *(const uint4*)(xb + (size_t)s1 * DIM + sub * 8);
            const uint4 u2 = *(const uint4*)(xb + (size_t)s2 * DIM + sub * 8);
            const uint4 u3 = *(const uint4*)(xb + (size_t)s3 * DIM + sub * 8);
            a0 += bf_lo(u0.x) * w0 + bf_lo(u1.x) * w1 + bf_lo(u2.x) * w2 + bf_lo(u3.x) * w3;
            a1 += bf_hi(u0.x) * w0 + bf_hi(u1.x) * w1 + bf_hi(u2.x) * w2 + bf_hi(u3.x) * w3;
            a2 += bf_lo(u0.y) * w0 + bf_lo(u1.y) * w1 + bf_lo(u2.y) * w2 + bf_lo(u3.y) * w3;
            a3 += bf_hi(u0.y) * w0 + bf_hi(u1.y) * w1 + bf_hi(u2.y) * w2 + bf_hi(u3.y) * w3;
            a4 += bf_lo(u0.z) * w0 + bf_lo(u1.z) * w1 + bf_lo(u2.z) * w2 + bf_lo(u3.z) * w3;
            a5 += bf_hi(u0.z) * w0 + bf_hi(u1.z) * w1 + bf_hi(u2.z) * w2 + bf_hi(u3.z) * w3;
            a6 += bf_lo(u0.w) * w0 + bf_lo(u1.w) * w1 + bf_lo(u2.w) * w2 + bf_lo(u3.w) * w3;
            a7 += bf_hi(u0.w) * w0 + bf_hi(u1.w) * w1 + bf_hi(u2.w) * w2 + bf_hi(u3.w) * w3;
        }
        for (; i < cnt; ++i) {
            const int   s = __shfl(idx_l, qb + i);
            const float w = __shfl(att_l, qb + i);
            const uint4 u = *(const uint4*)(xb + (size_t)s * DIM + sub * 8);
            a0 += bf_lo(u.x) * w;  a1 += bf_hi(u.x) * w;
            a2 += bf_lo(u.y) * w;  a3 += bf_hi(u.y) * w;
            a4 += bf_lo(u.z) * w;  a5 += bf_hi(u.z) * w;
            a6 += bf_lo(u.w) * w;  a7 += bf_hi(u.w) * w;
        }
    }

    uint4 o;
    o.x = ((unsigned)f2bf(a1) << 16) | (unsigned)f2bf(a0);
    o.y = ((unsigned)f2bf(a3) << 16) | (unsigned)f2bf(a2);
    o.z = ((unsigned)f2bf(a5) << 16) | (unsigned)f2bf(a4);
    o.w = ((unsigned)f2bf(a7) << 16) | (unsigned)f2bf(a6);
    *(uint4*)(aggb + (size_t)n * DIM + sub * 8) = o;
}

// ---------------------------------------------------------------------------
// x_new = relu([x || agg] @ Wg + bg) via bf16 MFMA (async LDS A-staging),
// next-layer attention dots fused into the epilogue.
// 64-row x 128-col tile, 33KB LDS -> 4 blocks/CU (16 waves/CU).
// ---------------------------------------------------------------------------
__global__ __launch_bounds__(256, 4) void gemm_mfma_kernel(
        unsigned short* __restrict__ xb, const unsigned short* __restrict__ aggb,
        const unsigned short* __restrict__ bfr, const float* __restrict__ bg,
        const float* __restrict__ wa_next, const float* __restrict__ ba_next,
        float* __restrict__ a_src, float* __restrict__ a_dst,
        float* __restrict__ xout_f32, int write_f32, int do_dots) {
    __shared__ unsigned short At[2][64 * 128];      // 32 KB
    __shared__ float psS[2][64], psD[2][64];        // 1 KB

    const int tid  = threadIdx.x;
    const int lane = tid & 63;
    const int wid  = tid >> 6;
    const int mbase = blockIdx.x * 64;

    // ---- stage both K-halves: 4 DMA instructions per half per wave ----
    #pragma unroll
    for (int h = 0; h < 2; ++h) {
        const unsigned short* s = h ? aggb : xb;
        #pragma unroll
        for (int i = 0; i < 4; ++i) {
            const int lrow = i * 16 + wid * 4 + (lane >> 4);       // 0..63
            const int c    = (lane & 15) ^ (lrow & 7);             // src chunk
            async16(s + (size_t)(mbase + lrow) * DIM + c * 8,
                    &At[h][(i * 16 + wid * 4) * 128]);             // uniform base
        }
    }

    const int waveM = wid >> 1, waveN = wid & 1;
    const int l16 = lane & 15, kq = lane >> 4;
    const unsigned short* bfw = bfr + (size_t)(waveN * 8) * 4 * 64 * 8;

    f32x4 acc[2][4] = {};
    short8 bcur[4], bnxt[4];

    // half0 staged (own 4 newest DMAs = half1 still in flight)
    asm volatile("s_waitcnt vmcnt(4)" ::: "memory");
    __builtin_amdgcn_s_barrier();

    #pragma unroll
    for (int nf = 0; nf < 4; ++nf)
        bcur[nf] = *(const short8*)(bfw + ((size_t)(0 * 4 + nf) * 64 + lane) * 8);

    #pragma unroll
    for (int ks = 0; ks < 8; ++ks) {
        if (ks == 4) {
            asm volatile("s_waitcnt vmcnt(0)" ::: "memory");
            __builtin_amdgcn_s_barrier();
        }
        if (ks < 7) {
            #pragma unroll
            for (int nf = 0; nf < 4; ++nf)
                bnxt[nf] = *(const short8*)(bfw + ((size_t)((ks + 1) * 4 + nf) * 64 + lane) * 8);
        }
        const int h = ks >> 2, ksl = ks & 3;
        short8 a[2];
        #pragma unroll
        for (int mf = 0; mf < 2; ++mf) {
            const int row   = waveM * 32 + mf * 16 + l16;          // 0..63
            const int chunk = (ksl * 4 + kq) ^ (row & 7);
            a[mf] = *(const short8*)&At[h][row * 128 + chunk * 8];
        }
        #pragma unroll
        for (int mf = 0; mf < 2; ++mf)
            #pragma unroll
            for (int nf = 0; nf < 4; ++nf)
                acc[mf][nf] = __builtin_amdgcn_mfma_f32_16x16x32_bf16(
                    a[mf], bcur[nf], acc[mf][nf], 0, 0, 0);
        if (ks < 7) {
            #pragma unroll
            for (int nf = 0; nf < 4; ++nf) bcur[nf] = bnxt[nf];
        }
    }

    // epilogue: bias + relu store (+ fused next-layer dots)
    const int rsub = kq * 4;
    float waS[4] = {0, 0, 0, 0}, waD[4] = {0, 0, 0, 0}, bias[4];
    #pragma unroll
    for (int nf = 0; nf < 4; ++nf) {
        const int col = waveN * 64 + nf * 16 + l16;
        bias[nf] = bg[col];
        if (do_dots) { waS[nf] = wa_next[col]; waD[nf] = wa_next[DIM + col]; }
    }
    #pragma unroll
    for (int mf = 0; mf < 2; ++mf) {
        #pragma unroll
        for (int j = 0; j < 4; ++j) {
            const int row = mbase + waveM * 32 + mf * 16 + rsub + j;
            float s = 0.0f, d = 0.0f;
            #pragma unroll
            for (int nf = 0; nf < 4; ++nf) {
                const int col = waveN * 64 + nf * 16 + l16;
                const float v = fmaxf(acc[mf][nf][j] + bias[nf], 0.0f);
                if (write_f32) {
                    if (row < NNODES) xout_f32[(size_t)row * DIM + col] = v;
                } else {
                    const unsigned short bv = f2bf(v);
                    const unsigned pb = (unsigned)(unsigned short)__shfl_xor((int)bv, 1);
                    if (!(l16 & 1) && row < NNODES)
                        *(unsigned*)(xb + (size_t)row * DIM + col) =
                            (unsigned)bv | (pb << 16);
                }
                s += v * waS[nf];
                d += v * waD[nf];
            }
            if (do_dots) {
                #pragma unroll
                for (int off = 1; off < 16; off <<= 1) {
                    s += __shfl_xor(s, off);
                    d += __shfl_xor(d, off);
                }
                if (l16 == 0) {
                    const int rl = waveM * 32 + mf * 16 + rsub + j;
                    psS[waveN][rl] = s;
                    psD[waveN][rl] = d;
                }
            }
        }
    }
    if (do_dots) {
        __syncthreads();
        if (tid < 64) {
            const int row = mbase + tid;
            if (row < NNODES) {
                a_src[row] = psS[0][tid] + psS[1][tid];
                a_dst[row] = psD[0][tid] + psD[1][tid] + ba_next[0];
            }
        }
    }
}

// ---------------------------------------------------------------------------
extern "C" void kernel_launch(void* const* d_in, const int* in_sizes, int n_in,
                              void* d_out, int out_size, void* d_ws, size_t ws_size,
                              hipStream_t stream) {
    const int*   edge = (const int*)d_in[0];       // [2, E]
    const float* ue   = (const float*)d_in[1];
    const float* ie   = (const float*)d_in[2];
    const float* Wa   = (const float*)d_in[3];     // [3, 256, 1]
    const float* ba   = (const float*)d_in[4];     // [3, 1]
    const float* Wg   = (const float*)d_in[5];     // [3, 256, 128]
    const float* bg   = (const float*)d_in[6];     // [3, 128]

    const int* src = edge;
    const int* dst = edge + NEDGES;

    float* x = (float*)d_out;                      // final f32 output

    // ---- workspace layout ----
    unsigned short* xb   = (unsigned short*)d_ws;            // NPAD*128 bf16
    unsigned short* aggb = xb + (size_t)NPAD * DIM;          // NPAD*128 bf16
    unsigned short* bfr  = aggb + (size_t)NPAD * DIM;        // 3*32768 bf16
    float* a_src      = (float*)(bfr + NLAYERS * 32768);     // NPAD f
    float* a_dst      = a_src + NPAD;                        // NPAD f
    int*   row_start  = (int*)(a_dst + NPAD);                // NPAD+256 i
    int*   csr_src    = row_start + NPAD + 256;              // NEDGES i
    unsigned* pairs   = (unsigned*)(csr_src + NEDGES);       // NEDGES u
    unsigned* counts  = pairs + NEDGES;                      // NBLK*NBUCK u
    unsigned* bbase   = counts + (size_t)NBLK * NBUCK;       // NBUCK+1 u

    concat_dots_kernel<<<(NNODES + 15) / 16, 256, 0, stream>>>(
        ue, ie, Wa, ba, xb, a_src, a_dst);
    wg_conv_kernel<<<(NLAYERS * 4096 + 255) / 256, 256, 0, stream>>>(Wg, bfr);

    // ---- binned CSR build ----
    bin_count_kernel<<<NBLK, 256, 0, stream>>>(dst, counts);
    prefix_kernel<<<1, 1024, 0, stream>>>(counts, bbase);
    bin_scatter_kernel<<<NBLK, 256, 0, stream>>>(src, dst, counts, bbase, pairs);
    bucket_csr_kernel<<<NBUCK, 256, 0, stream>>>(pairs, bbase, row_start, csr_src);

    const int gemm_blocks = (NNODES + 63) / 64;              // 1563
    const int pull_blocks = (NNODES + 15) / 16;              // 6250
    for (int l = 0; l < NLAYERS; ++l) {
        pull_agg_kernel<<<pull_blocks, 256, 0, stream>>>(
            row_start, csr_src, a_src, a_dst, xb, aggb);
        const int last = (l == NLAYERS - 1);
        gemm_mfma_kernel<<<gemm_blocks, 256, 0, stream>>>(
            xb, aggb, bfr + (size_t)l * 32768, bg + (size_t)l * DIM,
            Wa + (size_t)(l + 1 < NLAYERS ? l + 1 : 0) * 256,
            ba + (l + 1 < NLAYERS ? l + 1 : 0),
            a_src, a_dst, x, last ? 1 : 0, last ? 0 : 1);
    }
}

// Round 11
// 222.818 us; speedup vs baseline: 1.3696x; 1.0353x over previous
//
#include <hip/hip_runtime.h>
#include <cstddef>
#include <cstdint>

#define NUSERS 50000
#define NITEMS 50000
#define NNODES 100000
#define DIM    128
#define NLAYERS 3
#define NEDGES 600000
#define NPAD 100096           // 391*256  (>=96 rows of slack past NNODES)

#define EBLK  8192            // edges per binning block
#define NBLK  74              // ceil(600000/8192)
#define NBUCK 782             // ceil(100000/128), bucket = dst>>7

// merged prologue block ranges
#define PRO_CONCAT 6250       // concat_dots blocks
#define PRO_WG     48         // wg_conv blocks (3*4096/256)
#define PRO_TOTAL  (PRO_CONCAT + PRO_WG + NBLK)

typedef __attribute__((ext_vector_type(8))) short short8;
typedef __attribute__((ext_vector_type(4))) float f32x4;

__device__ __forceinline__ float bf_lo(unsigned u) { return __uint_as_float(u << 16); }
__device__ __forceinline__ float bf_hi(unsigned u) { return __uint_as_float(u & 0xffff0000u); }
__device__ __forceinline__ unsigned short f2bf(float f) {      // round-nearest-even
    unsigned b = __float_as_uint(f);
    return (unsigned short)((b + 0x7fffu + ((b >> 16) & 1u)) >> 16);
}

// async global->LDS 16B per lane; dst must be wave-uniform base (HW adds lane*16)
__device__ __forceinline__ void async16(const void* g, void* l) {
    __builtin_amdgcn_global_load_lds(
        (const __attribute__((address_space(1))) unsigned int*)(uintptr_t)g,
        (__attribute__((address_space(3))) unsigned int*)(unsigned int)(uintptr_t)l,
        16, 0, 0);
}

// ---------------------------------------------------------------------------
// merged prologue: [0,6250) concat+layer0 dots | [6250,6298) Wg conv |
//                  [6298,6372) edge bucket histogram
// ---------------------------------------------------------------------------
__global__ __launch_bounds__(256) void prologue_kernel(
        const float* __restrict__ ue, const float* __restrict__ ie,
        const float* __restrict__ Wa, const float* __restrict__ ba,
        const float* __restrict__ Wg, const int* __restrict__ dst,
        unsigned short* __restrict__ xb,
        float* __restrict__ a_src, float* __restrict__ a_dst,
        unsigned short* __restrict__ Bf, unsigned* __restrict__ counts) {
    __shared__ unsigned hist[NBUCK];
    const int blk = blockIdx.x;

    if (blk < PRO_CONCAT) {
        // ---- concat + layer-0 dots, quarter-wave per node ----
        const int n = blk * 16 + (threadIdx.x >> 4);
        if (n >= NNODES) return;
        const int sub = threadIdx.x & 15;
        const float* r = (n < NUSERS) ? (ue + (size_t)n * DIM)
                                      : (ie + (size_t)(n - NUSERS) * DIM);
        const float4 v0 = *(const float4*)(r + sub * 8);
        const float4 v1 = *(const float4*)(r + sub * 8 + 4);
        const float4 wl0 = *(const float4*)(Wa + sub * 8);
        const float4 wl1 = *(const float4*)(Wa + sub * 8 + 4);
        const float4 wh0 = *(const float4*)(Wa + DIM + sub * 8);
        const float4 wh1 = *(const float4*)(Wa + DIM + sub * 8 + 4);

        uint4 o;
        o.x = ((unsigned)f2bf(v0.y) << 16) | (unsigned)f2bf(v0.x);
        o.y = ((unsigned)f2bf(v0.w) << 16) | (unsigned)f2bf(v0.z);
        o.z = ((unsigned)f2bf(v1.y) << 16) | (unsigned)f2bf(v1.x);
        o.w = ((unsigned)f2bf(v1.w) << 16) | (unsigned)f2bf(v1.z);
        *(uint4*)(xb + (size_t)n * DIM + sub * 8) = o;

        float ps = v0.x * wl0.x + v0.y * wl0.y + v0.z * wl0.z + v0.w * wl0.w
                 + v1.x * wl1.x + v1.y * wl1.y + v1.z * wl1.z + v1.w * wl1.w;
        float pd = v0.x * wh0.x + v0.y * wh0.y + v0.z * wh0.z + v0.w * wh0.w
                 + v1.x * wh1.x + v1.y * wh1.y + v1.z * wh1.z + v1.w * wh1.w;
        #pragma unroll
        for (int off = 1; off < 16; off <<= 1) {
            ps += __shfl_xor(ps, off);
            pd += __shfl_xor(pd, off);
        }
        if (sub == 0) { a_src[n] = ps; a_dst[n] = pd + ba[0]; }
    } else if (blk < PRO_CONCAT + PRO_WG) {
        // ---- Bf[l][nb][ks][nf][lane][8] = Wg[l][k][col], B-fragment order ----
        const int tid = (blk - PRO_CONCAT) * 256 + threadIdx.x;
        if (tid >= NLAYERS * 4096) return;
        const int l    = tid >> 12;
        const int slot = tid & 4095;
        const int lane = slot & 63;
        const int t2   = slot >> 6;
        const int nf   = t2 & 3;
        const int t3   = t2 >> 2;
        const int ks   = t3 & 7;
        const int nb   = t3 >> 3;
        const int col  = nb * 64 + nf * 16 + (lane & 15);
        const int k0   = ks * 32 + (lane >> 4) * 8;
        const float* wsrc = Wg + (size_t)l * 256 * DIM;
        unsigned short o[8];
        #pragma unroll
        for (int j = 0; j < 8; ++j) o[j] = f2bf(wsrc[(size_t)(k0 + j) * DIM + col]);
        *(short8*)(Bf + (size_t)tid * 8) = *(short8*)o;
    } else {
        // ---- per-block LDS histogram of dst>>7 ----
        const int bblk = blk - PRO_CONCAT - PRO_WG;
        for (int i = threadIdx.x; i < NBUCK; i += 256) hist[i] = 0;
        __syncthreads();
        const int base = bblk * EBLK;
        const int end  = (base + EBLK < NEDGES) ? base + EBLK : NEDGES;
        for (int e = base + threadIdx.x; e < end; e += 256)
            atomicAdd(&hist[dst[e] >> 7], 1u);
        __syncthreads();
        for (int i = threadIdx.x; i < NBUCK; i += 256)
            counts[(size_t)bblk * NBUCK + i] = hist[i];
    }
}

// ---------------------------------------------------------------------------
// merged: per-bucket column prefix over blocks + exclusive scan of totals
// ---------------------------------------------------------------------------
__global__ __launch_bounds__(1024) void prefix_kernel(
        unsigned* __restrict__ counts, unsigned* __restrict__ bucketbase) {
    const int b = threadIdx.x;
    unsigned tot = 0;
    if (b < NBUCK) {
        for (int i = 0; i < NBLK; ++i) {
            const unsigned c = counts[(size_t)i * NBUCK + b];
            counts[(size_t)i * NBUCK + b] = tot;
            tot += c;
        }
    }
    const int lane = b & 63, w = b >> 6;
    unsigned s = tot;
    #pragma unroll
    for (int o = 1; o < 64; o <<= 1) {
        unsigned t = (unsigned)__shfl_up((int)s, o);
        if (lane >= o) s += t;
    }
    __shared__ unsigned wsum[16];
    if (lane == 63) wsum[w] = s;
    __syncthreads();
    unsigned add = 0;
    #pragma unroll
    for (int j = 0; j < 15; ++j) if (w > j) add += wsum[j];
    if (b < NBUCK) bucketbase[b] = s + add - tot;
    if (b == NBUCK - 1) bucketbase[NBUCK] = s + add;   // == NEDGES
}

__global__ __launch_bounds__(256) void bin_scatter_kernel(
        const int* __restrict__ src, const int* __restrict__ dst,
        const unsigned* __restrict__ counts, const unsigned* __restrict__ bucketbase,
        unsigned* __restrict__ pairs) {
    __shared__ unsigned off[NBUCK];
    for (int i = threadIdx.x; i < NBUCK; i += 256)
        off[i] = bucketbase[i] + counts[(size_t)blockIdx.x * NBUCK + i];
    __syncthreads();
    const int base = blockIdx.x * EBLK;
    const int end  = (base + EBLK < NEDGES) ? base + EBLK : NEDGES;
    for (int e = base + threadIdx.x; e < end; e += 256) {
        const int d = dst[e];
        const unsigned pos = atomicAdd(&off[d >> 7], 1u);
        pairs[pos] = ((unsigned)(d & 127) << 17) | (unsigned)src[e];
    }
}

__global__ __launch_bounds__(256) void bucket_csr_kernel(
        const unsigned* __restrict__ pairs, const unsigned* __restrict__ bucketbase,
        int* __restrict__ row_start, int* __restrict__ csr_src) {
    __shared__ unsigned deg[128], rs[128], fill[128];
    const int b = blockIdx.x;
    const unsigned seg0 = bucketbase[b], seg1 = bucketbase[b + 1];
    const int t = threadIdx.x;
    if (t < 128) deg[t] = 0;
    __syncthreads();
    for (unsigned i = seg0 + t; i < seg1; i += 256)
        atomicAdd(&deg[pairs[i] >> 17], 1u);
    __syncthreads();
    if (t < 128) rs[t] = deg[t];
    __syncthreads();
    #pragma unroll
    for (int o = 1; o < 128; o <<= 1) {           // Hillis-Steele inclusive
        unsigned tmp = 0;
        if (t < 128 && t >= o) tmp = rs[t - o];
        __syncthreads();
        if (t < 128) rs[t] += tmp;
        __syncthreads();
    }
    if (t < 128) {
        const unsigned excl = rs[t] - deg[t];
        fill[t] = excl;
        const int node = b * 128 + t;
        if (node < NNODES) row_start[node] = (int)(seg0 + excl);
    }
    __syncthreads();
    for (unsigned i = seg0 + t; i < seg1; i += 256) {
        const unsigned p = pairs[i];
        const unsigned r = atomicAdd(&fill[p >> 17], 1u);
        csr_src[seg0 + r] = (int)(p & 0x1ffffu);
    }
    if (b == 0 && t == 0) row_start[NNODES] = NEDGES;
}

// ---------------------------------------------------------------------------
// pull aggregation, quarter-wave (16 lanes = one node, 16B/lane), fused att
// ---------------------------------------------------------------------------
__global__ __launch_bounds__(256) void pull_agg_kernel(
        const int* __restrict__ row_start, const int* __restrict__ csr_src,
        const float* __restrict__ a_src, const float* __restrict__ a_dst,
        const unsigned short* __restrict__ xb, unsigned short* __restrict__ aggb) {
    const int n = blockIdx.x * 16 + (threadIdx.x >> 4);
    if (n >= NNODES) return;
    const int lane = threadIdx.x & 63;
    const int sub  = lane & 15;        // position within quarter
    const int qb   = lane & 48;        // quarter base lane
    const int beg = row_start[n], end = row_start[n + 1];
    const float adst = a_dst[n];

    float a0 = 0, a1 = 0, a2 = 0, a3 = 0, a4 = 0, a5 = 0, a6 = 0, a7 = 0;

    for (int base = beg; base < end; base += 16) {
        const int rem = end - base;
        const int cnt = rem < 16 ? rem : 16;
        int   idx_l = 0;
        float att_l = 0.0f;
        if (sub < cnt) {
            idx_l = csr_src[base + sub];
            att_l = 1.0f / (1.0f + __expf(-(a_src[idx_l] + adst)));
        }
        int i = 0;
        for (; i + 3 < cnt; i += 4) {
            const int   s0 = __shfl(idx_l, qb + i);
            const int   s1 = __shfl(idx_l, qb + i + 1);
            const int   s2 = __shfl(idx_l, qb + i + 2);
            const int   s3 = __shfl(idx_l, qb + i + 3);
            const float w0 = __shfl(att_l, qb + i);
            const float w1 = __shfl(att_l, qb + i + 1);
            const float w2 = __shfl(att_l, qb + i + 2);
            const float w3 = __shfl(att_l, qb + i + 3);
            const uint4 u0 = *(const uint4*)(xb + (size_t)s0 * DIM + sub * 8);
            const uint4 u1 = *(const uint4*)(xb + (size_t)s1 * DIM + sub * 8);
            const uint4 u2 = *(const uint4*)(xb + (size_t)s2 * DIM + sub * 8);
            const uint4 u3 = *(const uint4*)(xb + (size_t)s3 * DIM + sub * 8);
            a0 += bf_lo(u0.x) * w0 + bf_lo(u1.x) * w1 + bf_lo(u2.x) * w2 + bf_lo(u3.x) * w3;
            a1 += bf_hi(u0.x) * w0 + bf_hi(u1.x) * w1 + bf_hi(u2.x) * w2 + bf_hi(u3.x) * w3;
            a2 += bf_lo(u0.y) * w0 + bf_lo(u1.y) * w1 + bf_lo(u2.y) * w2 + bf_lo(u3.y) * w3;
            a3 += bf_hi(u0.y) * w0 + bf_hi(u1.y) * w1 + bf_hi(u2.y) * w2 + bf_hi(u3.y) * w3;
            a4 += bf_lo(u0.z) * w0 + bf_lo(u1.z) * w1 + bf_lo(u2.z) * w2 + bf_lo(u3.z) * w3;
            a5 += bf_hi(u0.z) * w0 + bf_hi(u1.z) * w1 + bf_hi(u2.z) * w2 + bf_hi(u3.z) * w3;
            a6 += bf_lo(u0.w) * w0 + bf_lo(u1.w) * w1 + bf_lo(u2.w) * w2 + bf_lo(u3.w) * w3;
            a7 += bf_hi(u0.w) * w0 + bf_hi(u1.w) * w1 + bf_hi(u2.w) * w2 + bf_hi(u3.w) * w3;
        }
        for (; i < cnt; ++i) {
            const int   s = __shfl(idx_l, qb + i);
            const float w = __shfl(att_l, qb + i);
            const uint4 u = *(const uint4*)(xb + (size_t)s * DIM + sub * 8);
            a0 += bf_lo(u.x) * w;  a1 += bf_hi(u.x) * w;
            a2 += bf_lo(u.y) * w;  a3 += bf_hi(u.y) * w;
            a4 += bf_lo(u.z) * w;  a5 += bf_hi(u.z) * w;
            a6 += bf_lo(u.w) * w;  a7 += bf_hi(u.w) * w;
        }
    }

    uint4 o;
    o.x = ((unsigned)f2bf(a1) << 16) | (unsigned)f2bf(a0);
    o.y = ((unsigned)f2bf(a3) << 16) | (unsigned)f2bf(a2);
    o.z = ((unsigned)f2bf(a5) << 16) | (unsigned)f2bf(a4);
    o.w = ((unsigned)f2bf(a7) << 16) | (unsigned)f2bf(a6);
    *(uint4*)(aggb + (size_t)n * DIM + sub * 8) = o;
}

// ---------------------------------------------------------------------------
// x_new = relu([x || agg] @ Wg + bg) via bf16 MFMA, next-layer dots fused.
// 32-row x 128-col tile, 4 waves each on a DISJOINT 32x32 sub-tile
// (no B duplication). LDS 17KB -> ~7-8 blocks/CU for latency hiding.
// 3125 blocks x 32 rows == 100000 exactly (no row guards).
// ---------------------------------------------------------------------------
__global__ __launch_bounds__(256, 7) void gemm_mfma_kernel(
        unsigned short* __restrict__ xb, const unsigned short* __restrict__ aggb,
        const unsigned short* __restrict__ bfr, const float* __restrict__ bg,
        const float* __restrict__ wa_next, const float* __restrict__ ba_next,
        float* __restrict__ a_src, float* __restrict__ a_dst,
        float* __restrict__ xout_f32, int write_f32, int do_dots) {
    __shared__ unsigned short At[2][32 * 128];      // 16 KB
    __shared__ float psS[4][32], psD[4][32];        // 1 KB

    const int tid  = threadIdx.x;
    const int lane = tid & 63;
    const int wid  = tid >> 6;
    const int mbase = blockIdx.x * 32;

    // ---- stage both K-halves: 2 DMA instructions per half per wave ----
    #pragma unroll
    for (int h = 0; h < 2; ++h) {
        const unsigned short* s = h ? aggb : xb;
        #pragma unroll
        for (int i = 0; i < 2; ++i) {
            const int lrow = i * 16 + wid * 4 + (lane >> 4);       // 0..31
            const int c    = (lane & 15) ^ (lrow & 7);             // src chunk
            async16(s + (size_t)(mbase + lrow) * DIM + c * 8,
                    &At[h][(i * 16 + wid * 4) * 128]);             // uniform base
        }
    }

    const int l16 = lane & 15, kq = lane >> 4;
    // wave covers cols [wid*32, wid*32+32)
    const unsigned short* bfw = bfr + (size_t)(wid >> 1) * (8 * 4 * 64 * 8);
    const int nfo = (wid & 1) * 2;

    f32x4 acc[2][2] = {};

    // half0 staged (2 newest DMAs = half1 still in flight)
    asm volatile("s_waitcnt vmcnt(2)" ::: "memory");
    __builtin_amdgcn_s_barrier();

    #pragma unroll
    for (int ks = 0; ks < 8; ++ks) {
        if (ks == 4) {
            asm volatile("s_waitcnt vmcnt(0)" ::: "memory");
            __builtin_amdgcn_s_barrier();
        }
        const int h = ks >> 2, ksl = ks & 3;
        short8 b[2], a[2];
        #pragma unroll
        for (int nf = 0; nf < 2; ++nf)
            b[nf] = *(const short8*)(bfw + ((size_t)(ks * 4 + nfo + nf) * 64 + lane) * 8);
        #pragma unroll
        for (int mf = 0; mf < 2; ++mf) {
            const int row   = mf * 16 + l16;                       // 0..31
            const int chunk = (ksl * 4 + kq) ^ (row & 7);
            a[mf] = *(const short8*)&At[h][row * 128 + chunk * 8];
        }
        #pragma unroll
        for (int mf = 0; mf < 2; ++mf)
            #pragma unroll
            for (int nf = 0; nf < 2; ++nf)
                acc[mf][nf] = __builtin_amdgcn_mfma_f32_16x16x32_bf16(
                    a[mf], b[nf], acc[mf][nf], 0, 0, 0);
    }

    // ---- epilogue: bias + relu store (+ fused next-layer dots) ----
    const int rsub = kq * 4;
    float waS[2] = {0, 0}, waD[2] = {0, 0}, bias[2];
    #pragma unroll
    for (int nf = 0; nf < 2; ++nf) {
        const int col = wid * 32 + nf * 16 + l16;
        bias[nf] = bg[col];
        if (do_dots) { waS[nf] = wa_next[col]; waD[nf] = wa_next[DIM + col]; }
    }
    #pragma unroll
    for (int mf = 0; mf < 2; ++mf) {
        #pragma unroll
        for (int j = 0; j < 4; ++j) {
            const int row = mbase + mf * 16 + rsub + j;
            float s = 0.0f, d = 0.0f;
            #pragma unroll
            for (int nf = 0; nf < 2; ++nf) {
                const int col = wid * 32 + nf * 16 + l16;
                const float v = fmaxf(acc[mf][nf][j] + bias[nf], 0.0f);
                if (write_f32) {
                    xout_f32[(size_t)row * DIM + col] = v;
                } else {
                    const unsigned short bv = f2bf(v);
                    const unsigned pb = (unsigned)(unsigned short)__shfl_xor((int)bv, 1);
                    if (!(l16 & 1))
                        *(unsigned*)(xb + (size_t)row * DIM + col) =
                            (unsigned)bv | (pb << 16);
                }
                s += v * waS[nf];
                d += v * waD[nf];
            }
            if (do_dots) {
                #pragma unroll
                for (int off = 1; off < 16; off <<= 1) {
                    s += __shfl_xor(s, off);
                    d += __shfl_xor(d, off);
                }
                if (l16 == 0) {
                    const int rl = mf * 16 + rsub + j;
                    psS[wid][rl] = s;
                    psD[wid][rl] = d;
                }
            }
        }
    }
    if (do_dots) {
        __syncthreads();
        if (tid < 32) {
            const int row = mbase + tid;
            a_src[row] = psS[0][tid] + psS[1][tid] + psS[2][tid] + psS[3][tid];
            a_dst[row] = psD[0][tid] + psD[1][tid] + psD[2][tid] + psD[3][tid]
                       + ba_next[0];
        }
    }
}

// ---------------------------------------------------------------------------
extern "C" void kernel_launch(void* const* d_in, const int* in_sizes, int n_in,
                              void* d_out, int out_size, void* d_ws, size_t ws_size,
                              hipStream_t stream) {
    const int*   edge = (const int*)d_in[0];       // [2, E]
    const float* ue   = (const float*)d_in[1];
    const float* ie   = (const float*)d_in[2];
    const float* Wa   = (const float*)d_in[3];     // [3, 256, 1]
    const float* ba   = (const float*)d_in[4];     // [3, 1]
    const float* Wg   = (const float*)d_in[5];     // [3, 256, 128]
    const float* bg   = (const float*)d_in[6];     // [3, 128]

    const int* src = edge;
    const int* dst = edge + NEDGES;

    float* x = (float*)d_out;                      // final f32 output

    // ---- workspace layout ----
    unsigned short* xb   = (unsigned short*)d_ws;            // NPAD*128 bf16
    unsigned short* aggb = xb + (size_t)NPAD * DIM;          // NPAD*128 bf16
    unsigned short* bfr  = aggb + (size_t)NPAD * DIM;        // 3*32768 bf16
    float* a_src      = (float*)(bfr + NLAYERS * 32768);     // NPAD f
    float* a_dst      = a_src + NPAD;                        // NPAD f
    int*   row_start  = (int*)(a_dst + NPAD);                // NPAD+256 i
    int*   csr_src    = row_start + NPAD + 256;              // NEDGES i
    unsigned* pairs   = (unsigned*)(csr_src + NEDGES);       // NEDGES u
    unsigned* counts  = pairs + NEDGES;                      // NBLK*NBUCK u
    unsigned* bbase   = counts + (size_t)NBLK * NBUCK;       // NBUCK+1 u

    // merged prologue: concat+dots | Wg conv | bucket histogram
    prologue_kernel<<<PRO_TOTAL, 256, 0, stream>>>(
        ue, ie, Wa, ba, Wg, dst, xb, a_src, a_dst, bfr, counts);

    // ---- binned CSR build ----
    prefix_kernel<<<1, 1024, 0, stream>>>(counts, bbase);
    bin_scatter_kernel<<<NBLK, 256, 0, stream>>>(src, dst, counts, bbase, pairs);
    bucket_csr_kernel<<<NBUCK, 256, 0, stream>>>(pairs, bbase, row_start, csr_src);

    const int gemm_blocks = NNODES / 32;                     // 3125 exact
    const int pull_blocks = (NNODES + 15) / 16;              // 6250
    for (int l = 0; l < NLAYERS; ++l) {
        pull_agg_kernel<<<pull_blocks, 256, 0, stream>>>(
            row_start, csr_src, a_src, a_dst, xb, aggb);
        const int last = (l == NLAYERS - 1);
        gemm_mfma_kernel<<<gemm_blocks, 256, 0, stream>>>(
            xb, aggb, bfr + (size_t)l * 32768, bg + (size_t)l * DIM,
            Wa + (size_t)(l + 1 < NLAYERS ? l + 1 : 0) * 256,
            ba + (l + 1 < NLAYERS ? l + 1 : 0),
            a_src, a_dst, x, last ? 1 : 0, last ? 0 : 1);
    }
}